// Round 4
// baseline (531.272 us; speedup 1.0000x reference)
//
#include <hip/hip_runtime.h>

// relpos embedding: z[i,j,:] = ((WT[d_res] + WT[66+d_tok]) + se*WT[132]) + WT[133+d_ch]
// N=1024, C_Z=128, IN_DIM=139.  Output 512 MiB fp32 -> store-BW-bound.
// Add order matches the JAX reference exactly.

#define N_TOK 1024
#define C_Z   128
#define IN_DIM 139
// LDS row pitch: 132 floats = 528 B -> 16B-aligned rows for float4 reads.
#define ROW_PAD 132
#define ROW_PAD4 (ROW_PAD / 4)   // 33 f32x4 per row

// clang native vector type: required by __builtin_nontemporal_store
// (HIP's float4 is a class and is rejected).
typedef float f32x4 __attribute__((ext_vector_type(4)));

__global__ __launch_bounds__(1024, 2)
void relpos_embed_kernel(const int* __restrict__ asym,
                         const int* __restrict__ resi,
                         const int* __restrict__ ent,
                         const int* __restrict__ tok,
                         const int* __restrict__ sym,
                         const float* __restrict__ W,   // [C_Z][IN_DIM] row-major
                         float* __restrict__ out)       // [N][N][C_Z]
{
    __shared__ float lds[IN_DIM * ROW_PAD];   // 73392 B (< 160 KiB gfx950 limit)

    const int tid = threadIdx.x;

    // Stage W transposed: lds[d][c] = W[c][d]. Global reads coalesced.
    for (int t = tid; t < C_Z * IN_DIM; t += 1024) {
        const int c = t / IN_DIM;
        const int d = t - c * IN_DIM;
        lds[d * ROW_PAD + c] = W[t];
    }
    __syncthreads();

    const int i  = blockIdx.x;             // one output row per block
    const int ai = asym[i];
    const int ri = resi[i];
    const int ei = ent[i];
    const int ti = tok[i];
    const int si = sym[i];

    const int pg = tid >> 5;               // 0..31 : j sub-index within group
    const int c4 = tid & 31;               // 0..31 : f32x4 slot in 128 channels

    const f32x4* lds4 = (const f32x4*)lds;            // row stride ROW_PAD4
    const f32x4 se_row = lds4[132 * ROW_PAD4 + c4];   // WT[132] kept in VGPRs

    f32x4* __restrict__ orow =
        (f32x4*)(out + (size_t)i * N_TOK * C_Z);      // 512 KB contiguous

    #pragma unroll 2
    for (int it = 0; it < 32; ++it) {
        const int j  = (it << 5) + pg;
        const int aj = asym[j];
        const int rj = resi[j];
        const int ej = ent[j];
        const int tj = tok[j];
        const int sj = sym[j];

        const bool sc = (ai == aj);
        const bool sr = (ri == rj);
        const bool se = (ei == ej);

        int dres = min(max(ri - rj + 32, 0), 64);
        if (!sc) dres = 65;
        int dtok = min(max(ti - tj + 32, 0), 64);
        if (!(sc && sr)) dtok = 65;
        int dch = min(max(si - sj + 2, 0), 4);
        if (!se) dch = 5;

        const f32x4 v0 = lds4[dres * ROW_PAD4 + c4];
        const f32x4 v1 = lds4[(66 + dtok) * ROW_PAD4 + c4];
        const f32x4 v2 = lds4[(133 + dch) * ROW_PAD4 + c4];

        // Reference association: ((v0 + v1) + se*WT[132]) + v2
        f32x4 v = v0 + v1;
        if (se) v += se_row;               // uniform per 32-lane group
        v += v2;

        // write-once stream past L3 -> nontemporal
        __builtin_nontemporal_store(v, orow + (size_t)j * (C_Z / 4) + c4);
    }
}

extern "C" void kernel_launch(void* const* d_in, const int* in_sizes, int n_in,
                              void* d_out, int out_size, void* d_ws, size_t ws_size,
                              hipStream_t stream) {
    const int*   asym = (const int*)d_in[0];
    const int*   resi = (const int*)d_in[1];
    const int*   ent  = (const int*)d_in[2];
    const int*   tok  = (const int*)d_in[3];
    const int*   sym  = (const int*)d_in[4];
    const float* W    = (const float*)d_in[5];
    float*       out  = (float*)d_out;

    relpos_embed_kernel<<<dim3(N_TOK), dim3(1024), 0, stream>>>(
        asym, resi, ent, tok, sym, W, out);
}